// Round 10
// baseline (2218.286 us; speedup 1.0000x reference)
//
#include <hip/hip_runtime.h>

#define D   42
#define ED  10
#define NU  16384
#define EU  32768
#define NV  20480
#define EV  40960
#define NT  (NU + NV)   // 36864
#define ET  (EU + EV)   // 73728
#define GJ  462         // 11 * 42 (10 h-channels + bias channel)
#define GP  464         // padded g/A row stride (116 float4)
#define STEPS 6

typedef float floatx4 __attribute__((ext_vector_type(4)));

// ---------------- prep: A[phase][i][k*42+o] = en2_w[k, i*42+o] (k<10) | en2_b (k=10) --------
__global__ void k_prep(const float* __restrict__ su_w2, const float* __restrict__ su_b2,
                       const float* __restrict__ sv_w2, const float* __restrict__ sv_b2,
                       float* __restrict__ A, float* __restrict__ mean) {
    int gid = blockIdx.x * 256 + threadIdx.x;
    if (gid < 128) mean[gid] = 0.f;
    if (gid >= 2 * D * GP) return;
    int phase = gid / (D * GP);
    int r = gid - phase * D * GP;
    int i = r / GP, j = r - i * GP;
    const float* w2 = phase ? sv_w2 : su_w2;
    const float* b2 = phase ? sv_b2 : su_b2;
    float v = 0.f;
    if (j < GJ) {
        int k = j / D, o = j - k * D;
        v = (k < ED) ? w2[k * (D * D) + i * D + o] : b2[i * D + o];
    }
    A[gid] = v;
}

// ---------------- CSR build --------------------------------------------------------------
__global__ void k_zcnt(int* __restrict__ p, int n) {
    int gid = blockIdx.x * 256 + threadIdx.x;
    if (gid < n) p[gid] = 0;
}

__global__ void k_count(const int* __restrict__ su_src, const int* __restrict__ su_dst,
                        const int* __restrict__ sv_src, const int* __restrict__ sv_dst,
                        int* __restrict__ outDeg, int* __restrict__ inDeg) {
    int e = blockIdx.x * 256 + threadIdx.x;
    if (e >= ET) return;
    int src, dst;
    if (e < EU) { src = su_src[e];           dst = su_dst[e]; }
    else        { src = sv_src[e - EU] + NU; dst = sv_dst[e - EU] + NU; }
    atomicAdd(&outDeg[src], 1);
    atomicAdd(&inDeg[dst], 1);
}

__global__ __launch_bounds__(1024) void k_scan(const int* __restrict__ degO, int* __restrict__ offO,
                                               const int* __restrict__ degI, int* __restrict__ offI) {
    __shared__ int part[1024];
    int t = threadIdx.x;
    for (int a = 0; a < 2; a++) {
        const int* deg = a ? degI : degO;
        int* off = a ? offI : offO;
        int loc[36];
        int base = t * 36;
        int s = 0;
        #pragma unroll
        for (int j = 0; j < 36; j++) { loc[j] = s; s += deg[base + j]; }
        part[t] = s;
        __syncthreads();
        for (int d = 1; d < 1024; d <<= 1) {
            int v = (t >= d) ? part[t - d] : 0;
            __syncthreads();
            part[t] += v;
            __syncthreads();
        }
        int excl = part[t] - s;
        #pragma unroll
        for (int j = 0; j < 36; j++) off[base + j] = excl + loc[j];
        if (t == 1023) off[NT] = excl + s;
        __syncthreads();
    }
}

__global__ void k_place(const int* __restrict__ su_src, const int* __restrict__ su_dst,
                        const int* __restrict__ sv_src, const int* __restrict__ sv_dst,
                        const int* __restrict__ offO, int* __restrict__ cntO,
                        const int* __restrict__ offI, int* __restrict__ cntI,
                        int* __restrict__ inList, int* __restrict__ srcSorted,
                        int* __restrict__ pOf) {
    int e = blockIdx.x * 256 + threadIdx.x;
    if (e >= ET) return;
    int src, dst;
    if (e < EU) { src = su_src[e];           dst = su_dst[e]; }
    else        { src = sv_src[e - EU] + NU; dst = sv_dst[e - EU] + NU; }
    int p = offO[src] + atomicAdd(&cntO[src], 1);
    int q = offI[dst] + atomicAdd(&cntI[dst], 1);
    inList[q] = p;
    srcSorted[p] = src;
    pOf[e] = p;
}

// ---------------- edge h: h_sorted[p] = [relu(ef@en1_w+en1_b), 1, 0] ------------------------
__global__ void k_edgeh(const float* __restrict__ su_e, const float* __restrict__ sv_e,
                        const float* __restrict__ su_w1, const float* __restrict__ su_b1,
                        const float* __restrict__ sv_w1, const float* __restrict__ sv_b1,
                        const int* __restrict__ pOf, float* __restrict__ hs) {
    __shared__ float w1s[2][ED * ED];
    __shared__ float b1s[2][ED];
    int tid = threadIdx.x;
    if (tid < ED * ED) { w1s[0][tid] = su_w1[tid]; w1s[1][tid] = sv_w1[tid]; }
    if (tid < ED)      { b1s[0][tid] = su_b1[tid]; b1s[1][tid] = sv_b1[tid]; }
    __syncthreads();
    int e = blockIdx.x * 256 + tid;
    if (e >= ET) return;
    int ph = (e >= EU);
    const float* ef = ph ? (sv_e + (size_t)(e - EU) * ED) : (su_e + (size_t)e * ED);
    float v[ED];
    #pragma unroll
    for (int j = 0; j < ED; j++) v[j] = ef[j];
    size_t p = (size_t)pOf[e] * 12;
    #pragma unroll
    for (int k = 0; k < ED; k++) {
        float s = b1s[ph][k];
        #pragma unroll
        for (int j = 0; j < ED; j++) s += v[j] * w1s[ph][j * ED + k];
        hs[p + k] = fmaxf(s, 0.f);
    }
    hs[p + 10] = 1.f;
    hs[p + 11] = 0.f;
}

// ---------------- fused step, 2 blocks/CU ---------------------------------------------------
// 32 nodes/block, 512 threads, ~80 KB LDS.
// phase 1: mT <- x (first) | relu(out + cb + gather msgR)      [transposed, stride 36]
// phase 2: out/outT <- relu(mT @ W + b)    (register-tiled, W in LDS)
// phase 3: g_lds <- outT @ A               (A from GLOBAL: broadcast over nodes -> L2)
// phase 4: msgW[p] <- h[p] . g_lds[src]    (own out-edges, contiguous)
__global__ __launch_bounds__(512, 2) void k_step(float* __restrict__ out,
                                                 const float* __restrict__ A,
                                                 const int* __restrict__ offO,
                                                 const int* __restrict__ srcSorted,
                                                 const float* __restrict__ hs,
                                                 float* __restrict__ msgW,
                                                 const float* __restrict__ msgR,
                                                 const int* __restrict__ offI,
                                                 const int* __restrict__ inList,
                                                 const float* __restrict__ su_x,
                                                 const float* __restrict__ sv_x,
                                                 const float* __restrict__ su_W, const float* __restrict__ su_b,
                                                 const float* __restrict__ sv_W, const float* __restrict__ sv_b,
                                                 const float* __restrict__ su_cb, const float* __restrict__ sv_cb,
                                                 int first) {
    __shared__ float g_lds[32 * GP];    // 59,392 B
    __shared__ float outT[D * 36];      //  6,048 B  ([o][nn])
    __shared__ float mT[48 * 36];       //  6,912 B  ([i][nn], i padded to 48 for f4 GEMM)
    __shared__ float w_lds[D * 48];     //  8,064 B  ([i][o], o padded 48)   total 80,416 B
    int tid = threadIdx.x;
    int n0 = blockIdx.x * 32;
    int ph = (n0 >= NU);

    // ---- stage W ----
    const float* W = ph ? sv_W : su_W;
    const float* b = ph ? sv_b : su_b;
    for (int idx = tid; idx < D * 48; idx += 512) {
        int i = idx / 48, o = idx - i * 48;
        w_lds[idx] = (o < D) ? W[i * D + o] : 0.f;
    }
    // zero mT pad rows (i = 42..47)
    for (int idx = tid; idx < 6 * 36; idx += 512) mT[D * 36 + idx] = 0.f;

    // ---- phase 1: build mT ----
    if (first) {
        const float* x = ph ? (sv_x + (size_t)(n0 - NU) * D) : (su_x + (size_t)n0 * D);
        for (int idx = tid; idx < 32 * D; idx += 512) {
            int i = idx % D, nn = idx / D;
            mT[i * 36 + nn] = x[(size_t)nn * D + i];
        }
    } else {
        const float* cb = ph ? sv_cb : su_cb;
        for (int idx = tid; idx < 32 * D; idx += 512) {
            int o = idx % D, nn = idx / D;
            int n = n0 + nn;
            int q0 = offI[n], q1 = offI[n + 1];
            float s = out[(size_t)n * D + o] + cb[o];
            for (int q = q0; q < q1; q++) s += msgR[(size_t)inList[q] * D + o];
            mT[o * 36 + nn] = fmaxf(s, 0.f);
        }
    }
    __syncthreads();

    // ---- phase 2: node GEMM, register-tiled: 44 workers = 4 node-f4-groups x 11 col-f4 ----
    // thread: 8 nodes (2 f4) x 4 cols (1 f4); per k: 2 mT b128 + 1 W b128 + 32 fmac
    if (tid < 44) {
        int cg = tid % 11, ng = tid / 11;
        const floatx4* mT4 = (const floatx4*)mT;
        const floatx4* w4  = (const floatx4*)w_lds;
        floatx4 accn[8];                 // [node][4 cols] : accn[r][c]
        #pragma unroll
        for (int r = 0; r < 8; r++) accn[r] = (floatx4)(0.f);
        for (int k = 0; k < D; k++) {
            floatx4 m0 = mT4[k * 9 + 2 * ng];
            floatx4 m1 = mT4[k * 9 + 2 * ng + 1];
            floatx4 wv = w4[k * 12 + cg];
            #pragma unroll
            for (int r = 0; r < 4; r++) {
                accn[r]     += wv * m0[r];
                accn[r + 4] += wv * m1[r];
            }
        }
        #pragma unroll
        for (int r = 0; r < 8; r++) {
            int nn = 8 * ng + r;
            #pragma unroll
            for (int c = 0; c < 4; c++) {
                int o = 4 * cg + c;
                if (o < D) {
                    float v = fmaxf(accn[r][c] + b[o], 0.f);
                    out[(size_t)(n0 + nn) * D + o] = v;
                    outT[o * 36 + nn] = v;
                }
            }
        }
    }
    __syncthreads();

    // ---- phase 3: g GEMM: 232 workers = 58 col-groups (2 f4) x 4 node-groups (8 nodes) ----
    // per k: 2 global A f4 (L2 broadcast) + 2 LDS f4 + 64 fmac
    if (tid < 232) {
        int cg = tid % 58, ng = tid / 58;
        const floatx4* Ag = (const floatx4*)(A + (ph ? D * GP : 0));
        const floatx4* oT4 = (const floatx4*)outT;
        floatx4 acc[8][2];
        #pragma unroll
        for (int r = 0; r < 8; r++) { acc[r][0] = (floatx4)(0.f); acc[r][1] = (floatx4)(0.f); }
        for (int k = 0; k < D; k++) {
            floatx4 a0 = Ag[k * 116 + 2 * cg];
            floatx4 a1 = Ag[k * 116 + 2 * cg + 1];
            floatx4 o0 = oT4[k * 9 + 2 * ng];
            floatx4 o1 = oT4[k * 9 + 2 * ng + 1];
            #pragma unroll
            for (int r = 0; r < 4; r++) {
                acc[r][0]     += a0 * o0[r];
                acc[r][1]     += a1 * o0[r];
                acc[r + 4][0] += a0 * o1[r];
                acc[r + 4][1] += a1 * o1[r];
            }
        }
        floatx4* gl4 = (floatx4*)g_lds;
        #pragma unroll
        for (int r = 0; r < 8; r++) {
            gl4[(8 * ng + r) * 116 + 2 * cg]     = acc[r][0];
            gl4[(8 * ng + r) * 116 + 2 * cg + 1] = acc[r][1];
        }
    }
    __syncthreads();

    // ---- phase 4: edge msg ----
    int p0 = offO[n0], p1 = offO[n0 + 32];
    int nwork = (p1 - p0) * D;
    for (int idx = tid; idx < nwork; idx += 512) {
        int pr = idx / D, o = idx - pr * D;
        int p = p0 + pr;
        int local = srcSorted[p] - n0;
        const float* hrow = hs + (size_t)p * 12;
        const float* grow = g_lds + local * GP;
        float s = 0.f;
        #pragma unroll
        for (int k = 0; k <= ED; k++) s += hrow[k] * grow[k * D + o];
        msgW[(size_t)p * D + o] = s;
    }
}

// ---------------- final update (no g needed) ------------------------------------------------
__global__ __launch_bounds__(256) void k_updF(const int* __restrict__ offI,
                                              const int* __restrict__ inList,
                                              const float* __restrict__ msg,
                                              float* __restrict__ out,
                                              const float* __restrict__ su_mw, const float* __restrict__ su_mb,
                                              const float* __restrict__ su_cb,
                                              const float* __restrict__ sv_mw, const float* __restrict__ sv_mb,
                                              const float* __restrict__ sv_cb) {
    __shared__ float mT[48 * 36];
    __shared__ float w_lds[D * 48];
    int tid = threadIdx.x;
    int n0 = blockIdx.x * 32;
    int ph = (n0 >= NU);
    const float* mw = ph ? sv_mw : su_mw;
    const float* mb = ph ? sv_mb : su_mb;
    const float* cb = ph ? sv_cb : su_cb;
    for (int idx = tid; idx < D * 48; idx += 256) {
        int i = idx / 48, o = idx - i * 48;
        w_lds[idx] = (o < D) ? mw[i * D + o] : 0.f;
    }
    for (int idx = tid; idx < 6 * 36; idx += 256) mT[D * 36 + idx] = 0.f;
    for (int idx = tid; idx < 32 * D; idx += 256) {
        int o = idx % D, nn = idx / D;
        int n = n0 + nn;
        int q0 = offI[n], q1 = offI[n + 1];
        float s = out[(size_t)n * D + o] + cb[o];
        for (int q = q0; q < q1; q++) s += msg[(size_t)inList[q] * D + o];
        mT[o * 36 + nn] = fmaxf(s, 0.f);
    }
    __syncthreads();
    if (tid < 44) {
        int cg = tid % 11, ng = tid / 11;
        const floatx4* mT4 = (const floatx4*)mT;
        const floatx4* w4  = (const floatx4*)w_lds;
        floatx4 accn[8];
        #pragma unroll
        for (int r = 0; r < 8; r++) accn[r] = (floatx4)(0.f);
        for (int k = 0; k < D; k++) {
            floatx4 m0 = mT4[k * 9 + 2 * ng];
            floatx4 m1 = mT4[k * 9 + 2 * ng + 1];
            floatx4 wv = w4[k * 12 + cg];
            #pragma unroll
            for (int r = 0; r < 4; r++) {
                accn[r]     += wv * m0[r];
                accn[r + 4] += wv * m1[r];
            }
        }
        #pragma unroll
        for (int r = 0; r < 8; r++) {
            int nn = 8 * ng + r;
            #pragma unroll
            for (int c = 0; c < 4; c++) {
                int o = 4 * cg + c;
                if (o < D) out[(size_t)(n0 + nn) * D + o] = fmaxf(accn[r][c] + mb[o], 0.f);
            }
        }
    }
}

// ---------------- reduce: mean[ph*42+o] += sum_n (out[n,o] + x[n,o]) ------------------------
__global__ void k_reduce(const float* __restrict__ out, const float* __restrict__ su_x,
                         const float* __restrict__ sv_x, float* __restrict__ mean) {
    __shared__ float sdata[6 * D];
    int tid = threadIdx.x;
    int bid = blockIdx.x;
    int n0, ph, nl0;
    const float* x;
    if (bid < NU / 128) { ph = 0; n0 = bid * 128;                 nl0 = n0;      x = su_x; }
    else                { ph = 1; n0 = NU + (bid - NU/128) * 128; nl0 = n0 - NU; x = sv_x; }
    if (tid < 6 * D) {
        int o = tid % D, r = tid / D;
        float acc = 0.f;
        for (int nn = r; nn < 128; nn += 6)
            acc += out[(size_t)(n0 + nn) * D + o] + x[(size_t)(nl0 + nn) * D + o];
        sdata[r * D + o] = acc;
    }
    __syncthreads();
    if (tid < D) {
        float tot = 0.f;
        #pragma unroll
        for (int r = 0; r < 6; r++) tot += sdata[r * D + tid];
        atomicAdd(&mean[ph * D + tid], tot);
    }
}

// ---------------- final MLP --------------------------------------------------------------
__global__ void k_mlp(const float* __restrict__ mean,
                      const float* __restrict__ fc1w, const float* __restrict__ fc1b,
                      const float* __restrict__ fc2w, const float* __restrict__ fc2b,
                      const float* __restrict__ fc3w, const float* __restrict__ fc3b,
                      float* __restrict__ outp) {
    __shared__ float c[4 * D];
    __shared__ float h1[256];
    __shared__ float h2[128];
    int t = threadIdx.x;
    if (t < 4 * D) {
        float v;
        if (t < 2 * D) v = mean[t < D ? t : t - D] * (1.f / NU);
        else { int q = t - 2 * D; v = mean[D + (q < D ? q : q - D)] * (1.f / NV); }
        c[t] = v;
    }
    __syncthreads();
    float s = fc1b[t];
    for (int j = 0; j < 4 * D; j++) s += c[j] * fc1w[j * 256 + t];
    h1[t] = fmaxf(s, 0.f);
    __syncthreads();
    if (t < 128) {
        float s2 = fc2b[t];
        for (int j = 0; j < 256; j++) s2 += h1[j] * fc2w[j * 128 + t];
        h2[t] = fmaxf(s2, 0.f);
    }
    __syncthreads();
    if (t == 0) {
        float s3 = fc3b[0];
        for (int j = 0; j < 128; j++) s3 += h2[j] * fc3w[j];
        outp[0] = s3;
    }
}

extern "C" void kernel_launch(void* const* d_in, const int* in_sizes, int n_in,
                              void* d_out, int out_size, void* d_ws, size_t ws_size,
                              hipStream_t stream) {
    const float* su_x     = (const float*)d_in[0];
    const float* su_e     = (const float*)d_in[1];
    const int*   su_src   = (const int*)d_in[2];
    const int*   su_dst   = (const int*)d_in[3];
    const float* sv_x     = (const float*)d_in[4];
    const float* sv_e     = (const float*)d_in[5];
    const int*   sv_src   = (const int*)d_in[6];
    const int*   sv_dst   = (const int*)d_in[7];
    const float* su_lin0w = (const float*)d_in[8];
    const float* su_lin0b = (const float*)d_in[9];
    const float* su_msgw  = (const float*)d_in[10];
    const float* su_msgb  = (const float*)d_in[11];
    const float* su_en1w  = (const float*)d_in[12];
    const float* su_en1b  = (const float*)d_in[13];
    const float* su_en2w  = (const float*)d_in[14];
    const float* su_en2b  = (const float*)d_in[15];
    const float* su_convb = (const float*)d_in[16];
    const float* sv_lin0w = (const float*)d_in[17];
    const float* sv_lin0b = (const float*)d_in[18];
    const float* sv_msgw  = (const float*)d_in[19];
    const float* sv_msgb  = (const float*)d_in[20];
    const float* sv_en1w  = (const float*)d_in[21];
    const float* sv_en1b  = (const float*)d_in[22];
    const float* sv_en2w  = (const float*)d_in[23];
    const float* sv_en2b  = (const float*)d_in[24];
    const float* sv_convb = (const float*)d_in[25];
    const float* fc1w     = (const float*)d_in[26];
    const float* fc1b     = (const float*)d_in[27];
    const float* fc2w     = (const float*)d_in[28];
    const float* fc2b     = (const float*)d_in[29];
    const float* fc3w     = (const float*)d_in[30];
    const float* fc3b     = (const float*)d_in[31];

    float* ws   = (float*)d_ws;
    float* out  = ws;                            // NT*D
    float* msg0 = out  + (size_t)NT * D;         // ET*D
    float* msg1 = msg0 + (size_t)ET * D;         // ET*D
    float* hs   = msg1 + (size_t)ET * D;         // ET*12
    float* A    = hs   + (size_t)ET * 12;        // 2*D*GP
    float* mean = A    + (size_t)2 * D * GP;     // 128
    int* ib     = (int*)(mean + 128);
    int* outDeg = ib;                            // NT
    int* inDeg  = outDeg + NT;                   // NT
    int* outCnt = inDeg  + NT;                   // NT
    int* inCnt  = outCnt + NT;                   // NT
    int* outOff = inCnt  + NT;                   // NT+1
    int* inOff  = outOff + (NT + 1);             // NT+1
    int* inList = inOff  + (NT + 1);             // ET
    int* srcS   = inList + ET;                   // ET
    int* pOf    = srcS   + ET;                   // ET

    // zero pred slot + the 16384x20480 interaction output
    hipMemsetAsync(d_out, 0, (size_t)out_size * sizeof(float), stream);

    k_prep<<<(2 * D * GP + 255) / 256, 256, 0, stream>>>(su_en2w, su_en2b, sv_en2w, sv_en2b, A, mean);

    // CSR build
    k_zcnt<<<(4 * NT + 255) / 256, 256, 0, stream>>>(outDeg, 4 * NT);
    k_count<<<(ET + 255) / 256, 256, 0, stream>>>(su_src, su_dst, sv_src, sv_dst, outDeg, inDeg);
    k_scan<<<1, 1024, 0, stream>>>(outDeg, outOff, inDeg, inOff);
    k_place<<<(ET + 255) / 256, 256, 0, stream>>>(su_src, su_dst, sv_src, sv_dst,
                                                  outOff, outCnt, inOff, inCnt, inList, srcS, pOf);
    k_edgeh<<<(ET + 255) / 256, 256, 0, stream>>>(su_e, sv_e, su_en1w, su_en1b, sv_en1w, sv_en1b, pOf, hs);

    float* mbuf[2] = { msg0, msg1 };
    for (int s = 0; s < STEPS; s++) {
        float* mw_ = mbuf[s & 1];
        float* mr_ = mbuf[(s & 1) ^ 1];
        if (s == 0) {
            k_step<<<NT / 32, 512, 0, stream>>>(out, A, outOff, srcS, hs, mw_, nullptr,
                                                inOff, inList, su_x, sv_x,
                                                su_lin0w, su_lin0b, sv_lin0w, sv_lin0b,
                                                su_convb, sv_convb, 1);
        } else {
            k_step<<<NT / 32, 512, 0, stream>>>(out, A, outOff, srcS, hs, mw_, mr_,
                                                inOff, inList, su_x, sv_x,
                                                su_msgw, su_msgb, sv_msgw, sv_msgb,
                                                su_convb, sv_convb, 0);
        }
    }
    k_updF<<<NT / 32, 256, 0, stream>>>(inOff, inList, mbuf[(STEPS - 1) & 1], out,
                                        su_msgw, su_msgb, su_convb, sv_msgw, sv_msgb, sv_convb);

    k_reduce<<<NU / 128 + NV / 128, 256, 0, stream>>>(out, su_x, sv_x, mean);
    k_mlp<<<1, 256, 0, stream>>>(mean, fc1w, fc1b, fc2w, fc2b, fc3w, fc3b, (float*)d_out);
}

// Round 11
// 921.966 us; speedup vs baseline: 2.4060x; 2.4060x over previous
//
#include <hip/hip_runtime.h>

#define D   42
#define ED  10
#define NU  16384
#define EU  32768
#define NV  20480
#define EV  40960
#define NT  (NU + NV)   // 36864
#define ET  (EU + EV)   // 73728
#define GJ  462         // 11 * 42
#define GP  464         // padded A/g row stride (116 float4)
#define STEPS 6
#define NBLK 256
#define OTS 164         // outT/mT node stride (41 float4)
#define SUB 16          // g sub-tile nodes

typedef float floatx4 __attribute__((ext_vector_type(4)));

// ---------------- prep: A[phase][i][k*42+o]; zero mean + barrier ----------------------------
__global__ void k_prep(const float* __restrict__ su_w2, const float* __restrict__ su_b2,
                       const float* __restrict__ sv_w2, const float* __restrict__ sv_b2,
                       float* __restrict__ A, float* __restrict__ mean) {
    int gid = blockIdx.x * 256 + threadIdx.x;
    if (gid < 128) mean[gid] = 0.f;          // also zeroes bar[] at mean+96
    if (gid >= 2 * D * GP) return;
    int phase = gid / (D * GP);
    int r = gid - phase * D * GP;
    int i = r / GP, j = r - i * GP;
    const float* w2 = phase ? sv_w2 : su_w2;
    const float* b2 = phase ? sv_b2 : su_b2;
    float v = 0.f;
    if (j < GJ) {
        int k = j / D, o = j - k * D;
        v = (k < ED) ? w2[k * (D * D) + i * D + o] : b2[i * D + o];
    }
    A[gid] = v;
}

// ---------------- CSR build ----------------------------------------------------------------
__global__ void k_zcnt(int* __restrict__ p, int n) {
    int gid = blockIdx.x * 256 + threadIdx.x;
    if (gid < n) p[gid] = 0;
}

__global__ void k_count(const int* __restrict__ su_src, const int* __restrict__ su_dst,
                        const int* __restrict__ sv_src, const int* __restrict__ sv_dst,
                        int* __restrict__ outDeg, int* __restrict__ inDeg) {
    int e = blockIdx.x * 256 + threadIdx.x;
    if (e >= ET) return;
    int src, dst;
    if (e < EU) { src = su_src[e];           dst = su_dst[e]; }
    else        { src = sv_src[e - EU] + NU; dst = sv_dst[e - EU] + NU; }
    atomicAdd(&outDeg[src], 1);
    atomicAdd(&inDeg[dst], 1);
}

__global__ __launch_bounds__(1024) void k_scan(const int* __restrict__ degO, int* __restrict__ offO,
                                               const int* __restrict__ degI, int* __restrict__ offI) {
    __shared__ int part[1024];
    int t = threadIdx.x;
    for (int a = 0; a < 2; a++) {
        const int* deg = a ? degI : degO;
        int* off = a ? offI : offO;
        int loc[36];
        int base = t * 36;
        int s = 0;
        #pragma unroll
        for (int j = 0; j < 36; j++) { loc[j] = s; s += deg[base + j]; }
        part[t] = s;
        __syncthreads();
        for (int d = 1; d < 1024; d <<= 1) {
            int v = (t >= d) ? part[t - d] : 0;
            __syncthreads();
            part[t] += v;
            __syncthreads();
        }
        int excl = part[t] - s;
        #pragma unroll
        for (int j = 0; j < 36; j++) off[base + j] = excl + loc[j];
        if (t == 1023) off[NT] = excl + s;
        __syncthreads();
    }
}

__global__ void k_place(const int* __restrict__ su_src, const int* __restrict__ su_dst,
                        const int* __restrict__ sv_src, const int* __restrict__ sv_dst,
                        const int* __restrict__ offO, int* __restrict__ cntO,
                        const int* __restrict__ offI, int* __restrict__ cntI,
                        int* __restrict__ inList, int* __restrict__ srcSorted,
                        int* __restrict__ pOf) {
    int e = blockIdx.x * 256 + threadIdx.x;
    if (e >= ET) return;
    int src, dst;
    if (e < EU) { src = su_src[e];           dst = su_dst[e]; }
    else        { src = sv_src[e - EU] + NU; dst = sv_dst[e - EU] + NU; }
    int p = offO[src] + atomicAdd(&cntO[src], 1);
    int q = offI[dst] + atomicAdd(&cntI[dst], 1);
    inList[q] = p;
    srcSorted[p] = src;
    pOf[e] = p;
}

// ---------------- edge h ------------------------------------------------------------------
__global__ void k_edgeh(const float* __restrict__ su_e, const float* __restrict__ sv_e,
                        const float* __restrict__ su_w1, const float* __restrict__ su_b1,
                        const float* __restrict__ sv_w1, const float* __restrict__ sv_b1,
                        const int* __restrict__ pOf, float* __restrict__ hs) {
    __shared__ float w1s[2][ED * ED];
    __shared__ float b1s[2][ED];
    int tid = threadIdx.x;
    if (tid < ED * ED) { w1s[0][tid] = su_w1[tid]; w1s[1][tid] = sv_w1[tid]; }
    if (tid < ED)      { b1s[0][tid] = su_b1[tid]; b1s[1][tid] = sv_b1[tid]; }
    __syncthreads();
    int e = blockIdx.x * 256 + tid;
    if (e >= ET) return;
    int ph = (e >= EU);
    const float* ef = ph ? (sv_e + (size_t)(e - EU) * ED) : (su_e + (size_t)e * ED);
    float v[ED];
    #pragma unroll
    for (int j = 0; j < ED; j++) v[j] = ef[j];
    size_t p = (size_t)pOf[e] * 12;
    #pragma unroll
    for (int k = 0; k < ED; k++) {
        float s = b1s[ph][k];
        #pragma unroll
        for (int j = 0; j < ED; j++) s += v[j] * w1s[ph][j * ED + k];
        hs[p + k] = fmaxf(s, 0.f);
    }
    hs[p + 10] = 1.f;
    hs[p + 11] = 0.f;
}

// ---------------- device helpers ----------------------------------------------------------
__device__ __forceinline__ void grid_barrier(int* bar, int gen) {
    __syncthreads();
    if (threadIdx.x == 0) {
        __threadfence();                                   // release my block's stores (device scope)
        int arrived = __hip_atomic_fetch_add(&bar[0], 1, __ATOMIC_ACQ_REL, __HIP_MEMORY_SCOPE_AGENT);
        if (arrived == NBLK - 1) {
            __hip_atomic_store(&bar[0], 0, __ATOMIC_RELAXED, __HIP_MEMORY_SCOPE_AGENT);
            __hip_atomic_fetch_add(&bar[1], 1, __ATOMIC_RELEASE, __HIP_MEMORY_SCOPE_AGENT);
        } else {
            while (__hip_atomic_load(&bar[1], __ATOMIC_ACQUIRE, __HIP_MEMORY_SCOPE_AGENT) <= gen)
                __builtin_amdgcn_s_sleep(2);
        }
        __threadfence();                                   // acquire: invalidate stale cached lines
    }
    __syncthreads();
}

// node GEMM: outT[o][nn] = relu(sum_i mT[i][nn] * w[i][o] + b[o]); workers og(11) x ng(NB/4)
__device__ __forceinline__ void node_gemm(const float* mT, const float* w_lds,
                                          const float* b_lds, float* outT, int NB) {
    int tid = threadIdx.x;
    int nw = 11 * (NB / 4);
    if (tid < nw) {
        int og = tid % 11, ng = tid / 11;
        const floatx4* m4 = (const floatx4*)mT;
        const floatx4* w4 = (const floatx4*)w_lds;
        floatx4 acc0 = (floatx4)(0.f), acc1 = (floatx4)(0.f);
        floatx4 acc2 = (floatx4)(0.f), acc3 = (floatx4)(0.f);
        for (int k = 0; k < D; k++) {
            floatx4 wv = w4[k * 11 + og];
            floatx4 mv = m4[k * 41 + ng];
            acc0 += wv * mv.x; acc1 += wv * mv.y; acc2 += wv * mv.z; acc3 += wv * mv.w;
        }
        int nn = ng * 4;
        #pragma unroll
        for (int c = 0; c < 4; c++) {
            int o = og * 4 + c;
            if (o < D) {
                float bo = b_lds[o];
                outT[o * OTS + nn]     = fmaxf(acc0[c] + bo, 0.f);
                outT[o * OTS + nn + 1] = fmaxf(acc1[c] + bo, 0.f);
                outT[o * OTS + nn + 2] = fmaxf(acc2[c] + bo, 0.f);
                outT[o * OTS + nn + 3] = fmaxf(acc3[c] + bo, 0.f);
            }
        }
    }
}

// ---------------- persistent 6-step kernel -------------------------------------------------
// 256 blocks (1/CU), 512 threads, ~143 KB LDS. su: blocks 0..127 x 128 nodes; sv: 128..255 x 160.
__global__ __launch_bounds__(512, 1) void k_main(
    const float* __restrict__ A,
    const int* __restrict__ offO, const int* __restrict__ srcS, const float* __restrict__ hs,
    float* __restrict__ msg0, float* __restrict__ msg1,
    const int* __restrict__ offI, const int* __restrict__ inList,
    const float* __restrict__ su_x, const float* __restrict__ sv_x,
    const float* __restrict__ su_l0w, const float* __restrict__ su_l0b,
    const float* __restrict__ sv_l0w, const float* __restrict__ sv_l0b,
    const float* __restrict__ su_mw, const float* __restrict__ su_mb,
    const float* __restrict__ sv_mw, const float* __restrict__ sv_mb,
    const float* __restrict__ su_cb, const float* __restrict__ sv_cb,
    float* __restrict__ mean, int* __restrict__ bar)
{
    __shared__ float A_lds[D * GP];      // 77,952 B
    __shared__ float outT[D * OTS];      // 27,552 B  [o][nn]
    __shared__ float scr[SUB * GP];      // 29,696 B  (g sub-tile | xT/mT [i][nn])
    __shared__ float w_lds[D * 44];      //  7,392 B
    __shared__ float b_lds[44];
    __shared__ float cb_lds[44];

    int tid = threadIdx.x;
    int blk = blockIdx.x;
    int ph  = (blk >= 128);
    int NB  = ph ? 160 : 128;
    int n0  = ph ? NU + (blk - 128) * 160 : blk * 128;
    int n0l = ph ? n0 - NU : n0;
    const float* x = ph ? sv_x : su_x;

    // stage A (once for the whole run)
    const floatx4* Ag = (const floatx4*)(A + (ph ? D * GP : 0));
    floatx4* Al4 = (floatx4*)A_lds;
    for (int i = tid; i < D * GP / 4; i += 512) Al4[i] = Ag[i];

    // stage lin0 weights + biases
    {
        const float* W0 = ph ? sv_l0w : su_l0w;
        const float* B0 = ph ? sv_l0b : su_l0b;
        const float* CB = ph ? sv_cb : su_cb;
        for (int i = tid; i < D * 44; i += 512) {
            int r = i / 44, c = i - r * 44;
            w_lds[i] = (c < D) ? W0[r * D + c] : 0.f;
        }
        if (tid < 44) {
            b_lds[tid]  = (tid < D) ? B0[tid] : 0.f;
            cb_lds[tid] = (tid < D) ? CB[tid] : 0.f;
        }
    }
    // load xT into scr
    for (int i = tid; i < NB * D; i += 512) {
        int nn = i / D, ii = i - nn * D;
        scr[ii * OTS + nn] = x[(size_t)(n0l + nn) * D + ii];
    }
    __syncthreads();

    // lin0: outT = relu(xT @ W0 + b0)
    node_gemm(scr, w_lds, b_lds, outT, NB);
    __syncthreads();

    // restage W = msg_w, b = msg_b
    {
        const float* WM = ph ? sv_mw : su_mw;
        const float* BM = ph ? sv_mb : su_mb;
        for (int i = tid; i < D * 44; i += 512) {
            int r = i / 44, c = i - r * 44;
            w_lds[i] = (c < D) ? WM[r * D + c] : 0.f;
        }
        if (tid < 44) b_lds[tid] = (tid < D) ? BM[tid] : 0.f;
    }

    int nsub = NB / SUB;
    for (int s = 0; s < STEPS; s++) {
        float* msgB = (s & 1) ? msg1 : msg0;     // emit and gather same buffer this step

        // ---- g + msg emit, per 16-node sub-tile ----
        for (int sub = 0; sub < nsub; sub++) {
            __syncthreads();                      // protects outT (update/lin0) + scr (prev emit)
            if (tid < 464) {
                int j4 = tid % 116, ng = tid / 116;
                const floatx4* oT4 = (const floatx4*)outT;
                int coff = sub * 4 + ng;
                floatx4 acc0 = (floatx4)(0.f), acc1 = (floatx4)(0.f);
                floatx4 acc2 = (floatx4)(0.f), acc3 = (floatx4)(0.f);
                for (int k = 0; k < D; k++) {
                    floatx4 a  = Al4[k * 116 + j4];
                    floatx4 ov = oT4[k * 41 + coff];
                    acc0 += a * ov.x; acc1 += a * ov.y; acc2 += a * ov.z; acc3 += a * ov.w;
                }
                floatx4* g4 = (floatx4*)scr;
                g4[(ng * 4 + 0) * 116 + j4] = acc0;
                g4[(ng * 4 + 1) * 116 + j4] = acc1;
                g4[(ng * 4 + 2) * 116 + j4] = acc2;
                g4[(ng * 4 + 3) * 116 + j4] = acc3;
            }
            __syncthreads();
            int sn0 = n0 + sub * SUB;
            int p0 = offO[sn0], p1 = offO[sn0 + SUB];
            int nwork = (p1 - p0) * D;
            for (int idx = tid; idx < nwork; idx += 512) {
                int pr = idx / D, o = idx - pr * D;
                int p = p0 + pr;
                int local = srcS[p] - sn0;
                const float* hrow = hs + (size_t)p * 12;
                const float* grow = scr + local * GP;
                float ssum = 0.f;
                #pragma unroll
                for (int k = 0; k <= ED; k++) ssum += hrow[k] * grow[k * D + o];
                msgB[(size_t)p * D + o] = ssum;
            }
        }

        grid_barrier(bar, s);

        // ---- gather + residual + relu -> mT(scr) ----
        for (int idx = tid; idx < NB * D; idx += 512) {
            int o = idx % D, nn = idx / D;
            int n = n0 + nn;
            int q0 = offI[n], q1 = offI[n + 1];
            float ssum = outT[o * OTS + nn] + cb_lds[o];
            for (int q = q0; q < q1; q++) ssum += msgB[(size_t)inList[q] * D + o];
            scr[o * OTS + nn] = fmaxf(ssum, 0.f);
        }
        __syncthreads();

        // ---- update: outT = relu(mT @ msg_w + b) ----
        node_gemm(scr, w_lds, b_lds, outT, NB);
        // next loop iteration's first __syncthreads protects outT/scr
    }
    __syncthreads();

    // ---- reduce own nodes: mean[ph*42+o] += sum_nn (outT[o][nn] + x[nn][o]) ----
    if (tid < 336) {
        int o = tid % D, r = tid / D;   // r < 8
        float acc = 0.f;
        for (int nn = r; nn < NB; nn += 8)
            acc += outT[o * OTS + nn] + x[(size_t)(n0l + nn) * D + o];
        scr[r * D + o] = acc;
    }
    __syncthreads();
    if (tid < D) {
        float tot = 0.f;
        #pragma unroll
        for (int r = 0; r < 8; r++) tot += scr[r * D + tid];
        atomicAdd(&mean[ph * D + tid], tot);
    }
}

// ---------------- final MLP ----------------------------------------------------------------
__global__ void k_mlp(const float* __restrict__ mean,
                      const float* __restrict__ fc1w, const float* __restrict__ fc1b,
                      const float* __restrict__ fc2w, const float* __restrict__ fc2b,
                      const float* __restrict__ fc3w, const float* __restrict__ fc3b,
                      float* __restrict__ outp) {
    __shared__ float c[4 * D];
    __shared__ float h1[256];
    __shared__ float h2[128];
    int t = threadIdx.x;
    if (t < 4 * D) {
        float v;
        if (t < 2 * D) v = mean[t < D ? t : t - D] * (1.f / NU);
        else { int q = t - 2 * D; v = mean[D + (q < D ? q : q - D)] * (1.f / NV); }
        c[t] = v;
    }
    __syncthreads();
    float s = fc1b[t];
    for (int j = 0; j < 4 * D; j++) s += c[j] * fc1w[j * 256 + t];
    h1[t] = fmaxf(s, 0.f);
    __syncthreads();
    if (t < 128) {
        float s2 = fc2b[t];
        for (int j = 0; j < 256; j++) s2 += h1[j] * fc2w[j * 128 + t];
        h2[t] = fmaxf(s2, 0.f);
    }
    __syncthreads();
    if (t == 0) {
        float s3 = fc3b[0];
        for (int j = 0; j < 128; j++) s3 += h2[j] * fc3w[j];
        outp[0] = s3;
    }
}

extern "C" void kernel_launch(void* const* d_in, const int* in_sizes, int n_in,
                              void* d_out, int out_size, void* d_ws, size_t ws_size,
                              hipStream_t stream) {
    const float* su_x     = (const float*)d_in[0];
    const float* su_e     = (const float*)d_in[1];
    const int*   su_src   = (const int*)d_in[2];
    const int*   su_dst   = (const int*)d_in[3];
    const float* sv_x     = (const float*)d_in[4];
    const float* sv_e     = (const float*)d_in[5];
    const int*   sv_src   = (const int*)d_in[6];
    const int*   sv_dst   = (const int*)d_in[7];
    const float* su_lin0w = (const float*)d_in[8];
    const float* su_lin0b = (const float*)d_in[9];
    const float* su_msgw  = (const float*)d_in[10];
    const float* su_msgb  = (const float*)d_in[11];
    const float* su_en1w  = (const float*)d_in[12];
    const float* su_en1b  = (const float*)d_in[13];
    const float* su_en2w  = (const float*)d_in[14];
    const float* su_en2b  = (const float*)d_in[15];
    const float* su_convb = (const float*)d_in[16];
    const float* sv_lin0w = (const float*)d_in[17];
    const float* sv_lin0b = (const float*)d_in[18];
    const float* sv_msgw  = (const float*)d_in[19];
    const float* sv_msgb  = (const float*)d_in[20];
    const float* sv_en1w  = (const float*)d_in[21];
    const float* sv_en1b  = (const float*)d_in[22];
    const float* sv_en2w  = (const float*)d_in[23];
    const float* sv_en2b  = (const float*)d_in[24];
    const float* sv_convb = (const float*)d_in[25];
    const float* fc1w     = (const float*)d_in[26];
    const float* fc1b     = (const float*)d_in[27];
    const float* fc2w     = (const float*)d_in[28];
    const float* fc2b     = (const float*)d_in[29];
    const float* fc3w     = (const float*)d_in[30];
    const float* fc3b     = (const float*)d_in[31];

    float* ws   = (float*)d_ws;
    float* msg0 = ws;                            // ET*D
    float* msg1 = msg0 + (size_t)ET * D;         // ET*D
    float* hs   = msg1 + (size_t)ET * D;         // ET*12
    float* A    = hs   + (size_t)ET * 12;        // 2*D*GP
    float* mean = A    + (size_t)2 * D * GP;     // 128 floats (bar lives at +96)
    int*   bar  = (int*)(mean + 96);             // 2 ints, zeroed by k_prep
    int* ib     = (int*)(mean + 128);
    int* outDeg = ib;                            // NT
    int* inDeg  = outDeg + NT;                   // NT
    int* outCnt = inDeg  + NT;                   // NT
    int* inCnt  = outCnt + NT;                   // NT
    int* outOff = inCnt  + NT;                   // NT+1
    int* inOff  = outOff + (NT + 1);             // NT+1
    int* inList = inOff  + (NT + 1);             // ET
    int* srcS   = inList + ET;                   // ET
    int* pOf    = srcS   + ET;                   // ET

    // zero pred slot + the 16384x20480 interaction output
    hipMemsetAsync(d_out, 0, (size_t)out_size * sizeof(float), stream);

    k_prep<<<(2 * D * GP + 255) / 256, 256, 0, stream>>>(su_en2w, su_en2b, sv_en2w, sv_en2b, A, mean);

    // CSR build
    k_zcnt<<<(4 * NT + 255) / 256, 256, 0, stream>>>(outDeg, 4 * NT);
    k_count<<<(ET + 255) / 256, 256, 0, stream>>>(su_src, su_dst, sv_src, sv_dst, outDeg, inDeg);
    k_scan<<<1, 1024, 0, stream>>>(outDeg, outOff, inDeg, inOff);
    k_place<<<(ET + 255) / 256, 256, 0, stream>>>(su_src, su_dst, sv_src, sv_dst,
                                                  outOff, outCnt, inOff, inCnt, inList, srcS, pOf);
    k_edgeh<<<(ET + 255) / 256, 256, 0, stream>>>(su_e, sv_e, su_en1w, su_en1b, sv_en1w, sv_en1b, pOf, hs);

    // persistent 6-step GNN (all 256 blocks co-resident; device-scope grid barrier per step)
    k_main<<<NBLK, 512, 0, stream>>>(A, outOff, srcS, hs, msg0, msg1, inOff, inList,
                                     su_x, sv_x,
                                     su_lin0w, su_lin0b, sv_lin0w, sv_lin0b,
                                     su_msgw, su_msgb, sv_msgw, sv_msgb,
                                     su_convb, sv_convb, mean, bar);

    k_mlp<<<1, 256, 0, stream>>>(mean, fc1w, fc1b, fc2w, fc2b, fc3w, fc3b, (float*)d_out);
}